// Round 1
// 405.454 us; speedup vs baseline: 1.0268x; 1.0268x over previous
//
#include <hip/hip_runtime.h>
#include <hip/hip_bf16.h>

typedef __bf16 bf16x8 __attribute__((ext_vector_type(8)));
typedef float  f32x4  __attribute__((ext_vector_type(4)));
typedef short  short4v __attribute__((ext_vector_type(4)));

#define B_SZ   2
#define T_SEQ  2048
#define C_EMB  2048
#define NH     16
#define HD     128
#define M_ROWS (B_SZ * T_SEQ)   /* 4096 */
#define N_QKV  (3 * C_EMB)      /* 6144 */
#define LQK    (2 * C_EMB)      /* 4096: qk buffer row length (q|k columns) */

static __device__ __forceinline__ unsigned short f2b(float f) {
  union { __hip_bfloat16 h; unsigned short u; } cv;
  cv.h = __float2bfloat16(f);
  return cv.u;
}
static __device__ __forceinline__ void store_out(float* p, float v) { *p = v; }
static __device__ __forceinline__ void store_out(unsigned short* p, float v) { *p = f2b(v); }

static __device__ __forceinline__ ushort4 load4_bf16(const float* p) {
  float4 v = *(const float4*)p;
  ushort4 o; o.x = f2b(v.x); o.y = f2b(v.y); o.z = f2b(v.z); o.w = f2b(v.w);
  return o;
}
static __device__ __forceinline__ ushort4 load4_bf16(const unsigned short* p) {
  return *(const ushort4*)p;
}

// async global->LDS, 16B/lane; LDS dest must be wave-uniform base + lane*16
static __device__ __forceinline__ void async_cp16(const unsigned short* g, unsigned short* l) {
  __builtin_amdgcn_global_load_lds((__attribute__((address_space(1))) void*)(g),
                                   (__attribute__((address_space(3))) void*)(l), 16, 0, 0);
}

// ---------------------------------------------------------------------------
// Shared epilogue helper for the 128-tile kernels. MODE 0: C = acc + bias.
// MODE 1 (qkv split): cols [0,4096) -> qk bf16; cols [4096,6144) -> vt (V^T).
// ---------------------------------------------------------------------------
template <int MODE, typename OutT>
static __device__ __forceinline__ void gemm_epilogue(
    f32x4 (&acc)[4][4], const float* __restrict__ bias,
    OutT* __restrict__ C, int ldc,
    unsigned short* __restrict__ qk, unsigned short* __restrict__ vt,
    int bm0, int bn0, int wm, int wn, int ln, int lq) {
  #pragma unroll
  for (int i = 0; i < 4; ++i) {
    const int row0 = bm0 + wm * 64 + i * 16 + lq * 4;
    #pragma unroll
    for (int j = 0; j < 4; ++j) {
      const int col = bn0 + wn * 64 + j * 16 + ln;
      const float bv = bias[col];
      if constexpr (MODE == 0) {
        #pragma unroll
        for (int r = 0; r < 4; ++r)
          store_out(&C[(size_t)(row0 + r) * ldc + col], acc[i][j][r] + bv);
      } else {
        if (bn0 < 2 * C_EMB) {
          #pragma unroll
          for (int r = 0; r < 4; ++r)
            qk[(size_t)(row0 + r) * LQK + col] = f2b(acc[i][j][r] + bv);
        } else {
          const int c2 = col - 2 * C_EMB;
          const int bb = row0 >> 11;
          const int t0 = row0 & (T_SEQ - 1);
          const int vrow = (bb * NH + (c2 >> 7)) * HD + (c2 & 127);
          ushort4 p;
          p.x = f2b(acc[i][j][0] + bv); p.y = f2b(acc[i][j][1] + bv);
          p.z = f2b(acc[i][j][2] + bv); p.w = f2b(acc[i][j][3] + bv);
          *(ushort4*)(vt + (size_t)vrow * T_SEQ + t0) = p;
        }
      }
    }
  }
}

// ---------------------------------------------------------------------------
// Tier A 128-tile GEMM (m97 structure) — retained for the proj GEMM.
// ---------------------------------------------------------------------------
template <int MODE, typename OutT>
__global__ __launch_bounds__(256) void gemm_bt(const unsigned short* __restrict__ A, int lda,
                                               const unsigned short* __restrict__ Bt,
                                               const float* __restrict__ bias,
                                               OutT* __restrict__ C, int ldc,
                                               unsigned short* __restrict__ qk,
                                               unsigned short* __restrict__ vt,
                                               int N, int K) {
  __shared__ __align__(16) unsigned short As[128 * 32];
  __shared__ __align__(16) unsigned short Bs[128 * 32];
  const int tid = threadIdx.x;
  const int wave = tid >> 6, lane = tid & 63;
  const int wm = wave >> 1, wn = wave & 1;
  const int ln = lane & 15, lq = lane >> 4;
  const int bm0 = blockIdx.y * 128, bn0 = blockIdx.x * 128;

  f32x4 acc[4][4];
  #pragma unroll
  for (int i = 0; i < 4; ++i)
    #pragma unroll
    for (int j = 0; j < 4; ++j) acc[i][j] = (f32x4){0.f, 0.f, 0.f, 0.f};

  const unsigned short* Ag = A  + (size_t)(bm0 + wave * 32 + (lane >> 2)) * lda + (lane & 3) * 8;
  const unsigned short* Bg = Bt + (size_t)(bn0 + wave * 32 + (lane >> 2)) * K   + (lane & 3) * 8;
  unsigned short* Al = As + wave * 1024 + lane * 8;
  unsigned short* Bl = Bs + wave * 1024 + lane * 8;

  for (int k0 = 0; k0 < K; k0 += 32) {
    async_cp16(Ag + k0, Al);
    async_cp16(Ag + k0 + 16 * lda, Al + 512);
    async_cp16(Bg + k0, Bl);
    async_cp16(Bg + k0 + 16 * K, Bl + 512);
    __syncthreads();
    bf16x8 af[4], bfv[4];
    #pragma unroll
    for (int i = 0; i < 4; ++i) {
      af[i]  = *(const bf16x8*)(As + (wm * 64 + i * 16 + ln) * 32 + lq * 8);
      bfv[i] = *(const bf16x8*)(Bs + (wn * 64 + i * 16 + ln) * 32 + lq * 8);
    }
    #pragma unroll
    for (int i = 0; i < 4; ++i)
      #pragma unroll
      for (int j = 0; j < 4; ++j)
        acc[i][j] = __builtin_amdgcn_mfma_f32_16x16x32_bf16(af[i], bfv[j], acc[i][j], 0, 0, 0);
    __syncthreads();
  }
  gemm_epilogue<MODE, OutT>(acc, bias, C, ldc, qk, vt, bm0, bn0, wm, wn, ln, lq);
}

// ---------------------------------------------------------------------------
// 256x256 8-phase GEMM (m201 template, plain HIP port): C = A * Bt^T + bias.
//   BM=BN=256, BK=64, 512 threads = 8 waves (2M x 4N), per-wave out 128x64.
//   LDS 128 KiB: 2 dbuf x 2 halves x [128 rows x 64 k] x {A,B} bf16.
//   Staging: global_load_lds width 16, one half-tile (2 loads/thread) per
//   phase; counted s_waitcnt vmcnt(4) ONLY at phases 4 and 8 (never 0).
//   LDS swizzle: short_off ^= (row&7)<<3, applied on BOTH sides (pre-swizzled
//   global source + swizzled ds_read) so global_load_lds's linear dest works.
//   Hazard schedule (K-tile t0=2i in buf0, t1=2i+1 in buf1):
//     ph1 (t0 r0c0): read A-r0(8)+B-c01(4); stage A(t1,h0)
//     ph2 (t0 r0c1): read B-c23(4);         stage A(t1,h1)
//     ph3 (t0 r1c0): read A-r1(8);          stage B(t0+2,h0)   [buf0 B free after ph2]
//     ph4 (t0 r1c1):                        stage B(t0+2,h1); vmcnt(4) -> t1 landed
//     ph5..ph8: same for t1; stages A(t0+2,h0/h1), B(t1+2,h0/h1); vmcnt(4)
//       at ph8 leaves only B(t1+2) in flight -> tile t0+2 landed for next ph1.
//   Tail iteration re-stages the current tiles (identical bytes -> benign).
// ---------------------------------------------------------------------------
#define BARRIER8 do { __builtin_amdgcn_s_barrier(); __builtin_amdgcn_sched_barrier(0); } while (0)
#define VMC4 asm volatile("s_waitcnt vmcnt(4)" ::: "memory")

#define STAGE_A8(t, h) do { \
    const unsigned short* g_ = Ag0 + (size_t)((h) * 128) * lda + (t) * 64; \
    unsigned short* l_ = ldsA + ((t) & 1) * 16384 + (h) * 8192 + tid * 8; \
    async_cp16(g_, l_); \
    async_cp16(g_ + (size_t)64 * lda, l_ + 4096); \
  } while (0)
#define STAGE_B8(t, h) do { \
    const unsigned short* g_ = Bg0 + (size_t)((h) * 128) * ldb + (t) * 64; \
    unsigned short* l_ = ldsB + ((t) & 1) * 16384 + (h) * 8192 + tid * 8; \
    async_cp16(g_, l_); \
    async_cp16(g_ + (size_t)64 * ldb, l_ + 4096); \
  } while (0)

#define LOADA8(ab, rq) do { \
    _Pragma("unroll") for (int rt_ = 0; rt_ < 4; ++rt_) { \
      af[rt_][0] = *(const bf16x8*)((ab) + (rq) * 4096 + rt_ * 1024 + kx0); \
      af[rt_][1] = *(const bf16x8*)((ab) + (rq) * 4096 + rt_ * 1024 + kx1); \
    } } while (0)
#define LOADB8(bb, cj0) do { \
    bv_[(cj0)][0]     = *(const bf16x8*)((bb) + (cj0) * 1024 + kx0); \
    bv_[(cj0)][1]     = *(const bf16x8*)((bb) + (cj0) * 1024 + kx1); \
    bv_[(cj0) + 1][0] = *(const bf16x8*)((bb) + ((cj0) + 1) * 1024 + kx0); \
    bv_[(cj0) + 1][1] = *(const bf16x8*)((bb) + ((cj0) + 1) * 1024 + kx1); \
  } while (0)
#define MFMAQ8(rq, cq) do { \
    __builtin_amdgcn_s_setprio(1); \
    _Pragma("unroll") for (int rt_ = 0; rt_ < 4; ++rt_) \
      _Pragma("unroll") for (int ct_ = 0; ct_ < 2; ++ct_) \
        _Pragma("unroll") for (int kk_ = 0; kk_ < 2; ++kk_) \
          acc[(rq) * 4 + rt_][(cq) * 2 + ct_] = __builtin_amdgcn_mfma_f32_16x16x32_bf16( \
              af[rt_][kk_], bv_[(cq) * 2 + ct_][kk_], acc[(rq) * 4 + rt_][(cq) * 2 + ct_], 0, 0, 0); \
    __builtin_amdgcn_s_setprio(0); \
  } while (0)

template <int MODE, typename OutT>
__global__ __launch_bounds__(512, 2) void gemm8_bt(
    const unsigned short* __restrict__ A, int lda,
    const unsigned short* __restrict__ Bt, int ldb,
    const float* __restrict__ bias,
    OutT* __restrict__ C, int ldc,
    unsigned short* __restrict__ qk, unsigned short* __restrict__ vt, int K) {
  __shared__ __align__(16) unsigned short lds8[65536];  // 128 KiB
  unsigned short* ldsA = lds8;
  unsigned short* ldsB = lds8 + 32768;

  const int tid = threadIdx.x;
  const int wave = tid >> 6, lane = tid & 63;
  const int wm = wave >> 2, wn = wave & 3;
  const int ln = lane & 15, lq = lane >> 4;

  const int nbx = gridDim.x;
  int bid = blockIdx.y * nbx + blockIdx.x;
  const int nwg = nbx * gridDim.y;
  if (!(nwg & 7)) bid = (bid & 7) * (nwg >> 3) + (bid >> 3);   // XCD swizzle (bijective: nwg%8==0)
  const int bm0 = (bid / nbx) * 256;
  const int bn0 = (bid % nbx) * 256;

  // staging addressing: thread covers rows (tid>>3) and (tid>>3)+64 of a half,
  // 16B slot (tid&7); pre-swizzled global k-offset = (slot ^ (row&7))*8 shorts.
  const int srow = tid >> 3;
  const int scol = ((tid & 7) ^ (srow & 7)) << 3;
  const unsigned short* Ag0 = A  + (size_t)(bm0 + srow) * lda + scol;
  const unsigned short* Bg0 = Bt + (size_t)(bn0 + srow) * ldb + scol;

  // compute-side swizzled k-offsets (shorts): (ko + lq*8) ^ ((ln&7)<<3)
  const int kx0 = (lq * 8) ^ ((ln & 7) << 3);
  const int kx1 = (32 + lq * 8) ^ ((ln & 7) << 3);
  const unsigned short* Ab0 = lds8 + wm * 8192 + ln * 64;
  const unsigned short* Bb0 = lds8 + 32768 + (wn >> 1) * 8192 + ((wn & 1) * 64 + ln) * 64;
  const unsigned short* Ab1 = Ab0 + 16384;
  const unsigned short* Bb1 = Bb0 + 16384;

  f32x4 acc[8][4];
  #pragma unroll
  for (int i = 0; i < 8; ++i)
    #pragma unroll
    for (int j = 0; j < 4; ++j) acc[i][j] = (f32x4){0.f, 0.f, 0.f, 0.f};
  bf16x8 af[4][2], bv_[4][2];

  // prologue: tile0 fully + tile1's B halves (A(t1) staged at ph1/ph2).
  STAGE_A8(0, 0); STAGE_A8(0, 1); STAGE_B8(0, 0); STAGE_B8(0, 1);
  STAGE_B8(1, 0); STAGE_B8(1, 1);
  VMC4;                       // 12 issued, wait<=4 -> tile0's 8 loads landed
  BARRIER8;

  const int NT = K >> 6, NI = NT >> 1;
  for (int i = 0; i < NI; ++i) {
    const int t1 = 2 * i + 1;
    const int ta = (2 * i + 2 < NT) ? (2 * i + 2) : (2 * i);  // tail: restage (same bytes)
    const int tb = (2 * i + 3 < NT) ? (2 * i + 3) : t1;
    // ---- K-tile t0 (buf0)
    LOADA8(Ab0, 0); LOADB8(Bb0, 0); STAGE_A8(t1, 0);        BARRIER8; MFMAQ8(0, 0); BARRIER8;  // ph1
    LOADB8(Bb0, 2);                 STAGE_A8(t1, 1);        BARRIER8; MFMAQ8(0, 1); BARRIER8;  // ph2
    LOADA8(Ab0, 1);                 STAGE_B8(ta, 0);        BARRIER8; MFMAQ8(1, 0); BARRIER8;  // ph3
                                    STAGE_B8(ta, 1); VMC4;  BARRIER8; MFMAQ8(1, 1); BARRIER8;  // ph4
    // ---- K-tile t1 (buf1)
    LOADA8(Ab1, 0); LOADB8(Bb1, 0); STAGE_A8(ta, 0);        BARRIER8; MFMAQ8(0, 0); BARRIER8;  // ph5
    LOADB8(Bb1, 2);                 STAGE_A8(ta, 1);        BARRIER8; MFMAQ8(0, 1); BARRIER8;  // ph6
    LOADA8(Ab1, 1);                 STAGE_B8(tb, 0);        BARRIER8; MFMAQ8(1, 0); BARRIER8;  // ph7
                                    STAGE_B8(tb, 1); VMC4;  BARRIER8; MFMAQ8(1, 1); BARRIER8;  // ph8
  }

  // ---- epilogue: wave rows bm0+wm*128+ri*16+lq*4+r, cols bn0+wn*64+cj*16+ln
  #pragma unroll
  for (int ri = 0; ri < 8; ++ri) {
    const int row0 = bm0 + wm * 128 + ri * 16 + lq * 4;
    #pragma unroll
    for (int cj = 0; cj < 4; ++cj) {
      const int col = bn0 + wn * 64 + cj * 16 + ln;
      const float bvs = bias[col];
      if constexpr (MODE == 0) {
        #pragma unroll
        for (int r = 0; r < 4; ++r)
          store_out(&C[(size_t)(row0 + r) * ldc + col], acc[ri][cj][r] + bvs);
      } else {
        if (bn0 < 2 * C_EMB) {  // q|k columns (block-uniform: 4096 % 256 == 0)
          #pragma unroll
          for (int r = 0; r < 4; ++r)
            qk[(size_t)(row0 + r) * LQK + col] = f2b(acc[ri][cj][r] + bvs);
        } else {                // v columns -> transposed store into vt
          const int c2 = col - 2 * C_EMB;
          const int bb = row0 >> 11;
          const int t0v = row0 & (T_SEQ - 1);
          const int vrow = (bb * NH + (c2 >> 7)) * HD + (c2 & 127);
          ushort4 p;
          p.x = f2b(acc[ri][cj][0] + bvs); p.y = f2b(acc[ri][cj][1] + bvs);
          p.z = f2b(acc[ri][cj][2] + bvs); p.w = f2b(acc[ri][cj][3] + bvs);
          *(ushort4*)(vt + (size_t)vrow * T_SEQ + t0v) = p;
        }
      }
    }
  }
}

// ---------------------------------------------------------------------------
// Tier B GEMM fallback (validated round-2 structure).
// ---------------------------------------------------------------------------
template <int MODE, typename AT, typename OutT>
__global__ __launch_bounds__(256) void gemm_any(const AT* __restrict__ A, int lda,
                                                const float* __restrict__ B, int ldb,
                                                const float* __restrict__ bias,
                                                OutT* __restrict__ C, int ldc,
                                                unsigned short* __restrict__ qk,
                                                unsigned short* __restrict__ vt,
                                                int N, int K) {
  __shared__ __align__(16) unsigned short As[128 * 32];
  __shared__ __align__(16) unsigned short Bs[128 * 32];
  __shared__ __align__(16) float Bstage[32 * 132];

  const int tid = threadIdx.x;
  const int wave = tid >> 6, lane = tid & 63;
  const int wm = wave >> 1, wn = wave & 1;
  const int ln = lane & 15, lq = lane >> 4;
  const int bm0 = blockIdx.y * 128, bn0 = blockIdx.x * 128;

  f32x4 acc[4][4];
  #pragma unroll
  for (int i = 0; i < 4; ++i)
    #pragma unroll
    for (int j = 0; j < 4; ++j) acc[i][j] = (f32x4){0.f, 0.f, 0.f, 0.f};

  for (int k0 = 0; k0 < K; k0 += 32) {
    #pragma unroll
    for (int j = 0; j < 4; ++j) {
      const int item = tid + j * 256;
      const int m = item >> 3;
      const int kf = (item & 7) * 4;
      *(ushort4*)(As + m * 32 + kf) = load4_bf16(A + (size_t)(bm0 + m) * lda + k0 + kf);
    }
    #pragma unroll
    for (int j = 0; j < 4; ++j) {
      const int item = tid + j * 256;
      const int kr = item >> 5;
      const int nf = (item & 31) * 4;
      *(float4*)(Bstage + kr * 132 + nf) =
          *(const float4*)(B + (size_t)(k0 + kr) * ldb + bn0 + nf);
    }
    __syncthreads();
    #pragma unroll
    for (int j = 0; j < 4; ++j) {
      const int item = tid + j * 256;
      const int n = item >> 3;
      const int kq = item & 7;
      const int k = kq * 4;
      ushort4 h4;
      h4.x = f2b(Bstage[(k + 0) * 132 + n]);
      h4.y = f2b(Bstage[(k + 1) * 132 + n]);
      h4.z = f2b(Bstage[(k + 2) * 132 + n]);
      h4.w = f2b(Bstage[(k + 3) * 132 + n]);
      *(ushort4*)(Bs + n * 32 + (((kq >> 1) ^ (n & 3)) << 3) + ((kq & 1) << 2)) = h4;
    }
    __syncthreads();
    bf16x8 af[4], bfv[4];
    #pragma unroll
    for (int i = 0; i < 4; ++i) {
      af[i] = *(const bf16x8*)(As + (wm * 64 + i * 16 + ln) * 32 + lq * 8);
      const int n = wn * 64 + i * 16 + ln;
      bfv[i] = *(const bf16x8*)(Bs + n * 32 + ((lq ^ (n & 3)) << 3));
    }
    #pragma unroll
    for (int i = 0; i < 4; ++i)
      #pragma unroll
      for (int j = 0; j < 4; ++j)
        acc[i][j] = __builtin_amdgcn_mfma_f32_16x16x32_bf16(af[i], bfv[j], acc[i][j], 0, 0, 0);
    __syncthreads();
  }
  gemm_epilogue<MODE, OutT>(acc, bias, C, ldc, qk, vt, bm0, bn0, wm, wn, ln, lq);
}

// ---------------------------------------------------------------- prep (Tier A)
__global__ __launch_bounds__(256) void cast_x_bf16(const float4* __restrict__ in,
                                                   ushort4* __restrict__ out, int n4) {
  int i = blockIdx.x * 256 + threadIdx.x;
  if (i < n4) {
    float4 v = in[i];
    ushort4 o; o.x = f2b(v.x); o.y = f2b(v.y); o.z = f2b(v.z); o.w = f2b(v.w);
    out[i] = o;
  }
}

__global__ __launch_bounds__(256) void transpose_cast(const float* __restrict__ in,
                                                      unsigned short* __restrict__ out,
                                                      int R, int Cc) {
  __shared__ float t[32][33];
  const int bx = blockIdx.x * 32, by = blockIdx.y * 32;
  const int tx = threadIdx.x & 31, ty = threadIdx.x >> 5;
  #pragma unroll
  for (int j = 0; j < 32; j += 8)
    t[ty + j][tx] = in[(size_t)(by + ty + j) * Cc + bx + tx];
  __syncthreads();
  #pragma unroll
  for (int j = 0; j < 32; j += 8)
    out[(size_t)(bx + ty + j) * R + by + tx] = f2b(t[tx][ty + j]);
}

// ---------------------------------------------------------------------------
// Flash attention: transposed-S, max-free softmax, 8-wave (512-thread) blocks.
// (unchanged this round — next optimization target)
// ---------------------------------------------------------------------------
__global__ __launch_bounds__(512, 4) void attn_st(unsigned short* __restrict__ qk,
                                                  const unsigned short* __restrict__ vt) {
  __shared__ __align__(16) unsigned short smem[17920];
  unsigned short* Ks  = smem;            // K tile [key][d], pad 136
  unsigned short* VTs = smem + 64 * 136; // V^T tile [d][key], pad 72

  const int tid = threadIdx.x;
  const int w = tid >> 6, lane = tid & 63;
  const int ln = lane & 15, lq = lane >> 4;
  const int b = blockIdx.z, h = blockIdx.y;
  const int j = (b == 0) ? (15 - (int)blockIdx.x) : (int)blockIdx.x;
  const int qb0 = j * 128;
  const float EXPSC = 0.08838834764831845f * 1.4426950408889634f;

  const int wq0 = qb0 + w * 16;
  const int qg = wq0 + ln;
  const unsigned short* Qp = qk + (size_t)(b * T_SEQ + qg) * LQK + h * HD + lq * 8;
  bf16x8 bq[4];
  #pragma unroll
  for (int ks = 0; ks < 4; ++ks) bq[ks] = *(const bf16x8*)(Qp + ks * 32);

  f32x4 ot[8];
  #pragma unroll
  for (int dt = 0; dt < 8; ++dt) ot[dt] = (f32x4){0.f, 0.f, 0.f, 0.f};
  float l_i = 0.f;

  const int kbmax = 2 * j + 1;
  for (int kb = 0; kb <= kbmax; ++kb) {
    __syncthreads();
    #pragma unroll
    for (int jj = 0; jj < 2; ++jj) {
      const int s = tid + jj * 512;
      const int row = s >> 4, c8 = s & 15;
      *(uint4*)(Ks + row * 136 + c8 * 8) =
          *(const uint4*)(qk + (size_t)(b * T_SEQ + kb * 64 + row) * LQK + C_EMB + h * HD + c8 * 8);
    }
    #pragma unroll
    for (int jj = 0; jj < 2; ++jj) {
      const int s = tid + jj * 512;
      const int row = s >> 3, c8 = s & 7;
      *(uint4*)(VTs + row * 72 + c8 * 8) =
          *(const uint4*)(vt + ((size_t)(b * NH + h) * HD + row) * T_SEQ + kb * 64 + c8 * 8);
    }
    __syncthreads();

    if (kb * 64 <= wq0 + 15) {
      const bool diag = (kb * 64 + 63 > wq0);

      f32x4 st[4];
      #pragma unroll
      for (int kt = 0; kt < 4; ++kt) {
        st[kt] = (f32x4){0.f, 0.f, 0.f, 0.f};
        #pragma unroll
        for (int ks = 0; ks < 4; ++ks) {
          bf16x8 ak = *(const bf16x8*)(Ks + (kt * 16 + ln) * 136 + ks * 32 + lq * 8);
          st[kt] = __builtin_amdgcn_mfma_f32_16x16x32_bf16(ak, bq[ks], st[kt], 0, 0, 0);
        }
      }

      short4v pf[4];
      #pragma unroll
      for (int kt = 0; kt < 4; ++kt)
        #pragma unroll
        for (int r = 0; r < 4; ++r) {
          float p = __builtin_exp2f(st[kt][r] * EXPSC);
          if (diag && (kb * 64 + kt * 16 + lq * 4 + r > qg)) p = 0.f;
          l_i += p;
          pf[kt][r] = (short)f2b(p);
        }

      #pragma unroll
      for (int kt = 0; kt < 4; ++kt)
        #pragma unroll
        for (int dt = 0; dt < 8; ++dt) {
          short4v av = *(const short4v*)(VTs + (dt * 16 + ln) * 72 + kt * 16 + lq * 4);
          ot[dt] = __builtin_amdgcn_mfma_f32_16x16x16bf16_1k(av, pf[kt], ot[dt], 0, 0, 0);
        }
    }
  }

  l_i += __shfl_xor(l_i, 16);
  l_i += __shfl_xor(l_i, 32);
  const float inv = 1.f / l_i;

  __syncthreads();
  #pragma unroll
  for (int dt = 0; dt < 8; ++dt) {
    ushort4 p4;
    p4.x = f2b(ot[dt][0] * inv); p4.y = f2b(ot[dt][1] * inv);
    p4.z = f2b(ot[dt][2] * inv); p4.w = f2b(ot[dt][3] * inv);
    *(ushort4*)(smem + (w * 16 + ln) * 136 + dt * 16 + lq * 4) = p4;
  }
  __syncthreads();
  #pragma unroll
  for (int jj = 0; jj < 4; ++jj) {
    const int s = tid + jj * 512;
    const int row = s >> 4, c8 = s & 15;
    *(uint4*)(qk + (size_t)(b * T_SEQ + qb0 + row) * LQK + h * HD + c8 * 8) =
        *(const uint4*)(smem + row * 136 + c8 * 8);
  }
}

// ---------------------------------------------------------------- launch
extern "C" void kernel_launch(void* const* d_in, const int* in_sizes, int n_in,
                              void* d_out, int out_size, void* d_ws, size_t ws_size,
                              hipStream_t stream) {
  (void)in_sizes; (void)n_in; (void)out_size;
  const float* x      = (const float*)d_in[0];
  const float* W_attn = (const float*)d_in[1];
  const float* b_attn = (const float*)d_in[2];
  const float* W_proj = (const float*)d_in[3];
  const float* b_proj = (const float*)d_in[4];
  float* out = (float*)d_out;

  char* ws = (char*)d_ws;
  unsigned short* qk = (unsigned short*)(ws);                  // 32 MiB [4096][4096]
  unsigned short* vt = (unsigned short*)(ws + 33554432);       // 16 MiB [B*NH*HD][T]
  unsigned short* xb  = (unsigned short*)(ws + 50331648);      // 16 MiB x bf16
  unsigned short* WaT = (unsigned short*)(ws + 67108864);      // 24 MiB W_attn^T bf16
  unsigned short* WpT = (unsigned short*)(ws + 92274688);      // 8  MiB W_proj^T bf16
  const bool tierA = (ws_size >= 100663296);                   // 96 MiB

  if (tierA) {
    const int n_x = M_ROWS * C_EMB;
    cast_x_bf16<<<n_x / 4 / 256, 256, 0, stream>>>((const float4*)x, (ushort4*)xb, n_x / 4);
    transpose_cast<<<dim3(N_QKV / 32, C_EMB / 32), 256, 0, stream>>>(W_attn, WaT, C_EMB, N_QKV);
    transpose_cast<<<dim3(C_EMB / 32, C_EMB / 32), 256, 0, stream>>>(W_proj, WpT, C_EMB, C_EMB);
    gemm8_bt<1, unsigned short><<<dim3(N_QKV / 256, M_ROWS / 256), 512, 0, stream>>>(
        xb, C_EMB, WaT, C_EMB, b_attn, (unsigned short*)nullptr, 0, qk, vt, C_EMB);
  } else {
    gemm_any<1, float, unsigned short><<<dim3(N_QKV / 128, M_ROWS / 128), 256, 0, stream>>>(
        x, C_EMB, W_attn, N_QKV, b_attn, (unsigned short*)nullptr, 0, qk, vt, N_QKV, C_EMB);
  }

  attn_st<<<dim3(16, NH, B_SZ), 512, 0, stream>>>(qk, vt);

  if (tierA) {
    gemm_bt<0, float><<<dim3(C_EMB / 128, M_ROWS / 128), 256, 0, stream>>>(
        qk, LQK, WpT, b_proj, out, C_EMB, nullptr, nullptr, C_EMB, C_EMB);
  } else {
    gemm_any<0, unsigned short, float><<<dim3(C_EMB / 128, M_ROWS / 128), 256, 0, stream>>>(
        qk, LQK, W_proj, C_EMB, b_proj, out, C_EMB, nullptr, nullptr, C_EMB, C_EMB);
  }
}

// Round 3
// 396.864 us; speedup vs baseline: 1.0490x; 1.0216x over previous
//
#include <hip/hip_runtime.h>
#include <hip/hip_bf16.h>

typedef __bf16 bf16x8 __attribute__((ext_vector_type(8)));
typedef float  f32x4  __attribute__((ext_vector_type(4)));
typedef short  short4v __attribute__((ext_vector_type(4)));

#define B_SZ   2
#define T_SEQ  2048
#define C_EMB  2048
#define NH     16
#define HD     128
#define M_ROWS (B_SZ * T_SEQ)   /* 4096 */
#define N_QKV  (3 * C_EMB)      /* 6144 */
#define LQK    (2 * C_EMB)      /* 4096: qk buffer row length (q|k columns) */

// Global K layout (qk cols [2048,4096)): within-head col c stored at
//   c ^ ((t&7)<<3)   (t = key row). Global V^T layout (vt): within each
// 64-key tile, key col t stored at t ^ ((d&7)<<3) (d = vt row & 127).
// Both swizzles let attn stage tiles LINEARLY via global_load_lds and read
// conflict-free with the same XOR (both-sides involution).

static __device__ __forceinline__ unsigned short f2b(float f) {
  union { __hip_bfloat16 h; unsigned short u; } cv;
  cv.h = __float2bfloat16(f);
  return cv.u;
}
static __device__ __forceinline__ void store_out(float* p, float v) { *p = v; }
static __device__ __forceinline__ void store_out(unsigned short* p, float v) { *p = f2b(v); }

static __device__ __forceinline__ ushort4 load4_bf16(const float* p) {
  float4 v = *(const float4*)p;
  ushort4 o; o.x = f2b(v.x); o.y = f2b(v.y); o.z = f2b(v.z); o.w = f2b(v.w);
  return o;
}
static __device__ __forceinline__ ushort4 load4_bf16(const unsigned short* p) {
  return *(const ushort4*)p;
}

// async global->LDS, 16B/lane; LDS dest must be wave-uniform base + lane*16
static __device__ __forceinline__ void async_cp16(const unsigned short* g, unsigned short* l) {
  __builtin_amdgcn_global_load_lds((__attribute__((address_space(1))) void*)(g),
                                   (__attribute__((address_space(3))) void*)(l), 16, 0, 0);
}

// ---------------------------------------------------------------------------
// Shared epilogue helper for the 128-tile kernels. MODE 0: C = acc + bias.
// MODE 1 (qkv split): q cols linear; k cols swizzled; v cols -> vt swizzled.
// ---------------------------------------------------------------------------
template <int MODE, typename OutT>
static __device__ __forceinline__ void gemm_epilogue(
    f32x4 (&acc)[4][4], const float* __restrict__ bias,
    OutT* __restrict__ C, int ldc,
    unsigned short* __restrict__ qk, unsigned short* __restrict__ vt,
    int bm0, int bn0, int wm, int wn, int ln, int lq) {
  #pragma unroll
  for (int i = 0; i < 4; ++i) {
    const int row0 = bm0 + wm * 64 + i * 16 + lq * 4;
    #pragma unroll
    for (int j = 0; j < 4; ++j) {
      const int col = bn0 + wn * 64 + j * 16 + ln;
      const float bv = bias[col];
      if constexpr (MODE == 0) {
        #pragma unroll
        for (int r = 0; r < 4; ++r)
          store_out(&C[(size_t)(row0 + r) * ldc + col], acc[i][j][r] + bv);
      } else {
        if (bn0 < C_EMB) {              // q columns: linear
          #pragma unroll
          for (int r = 0; r < 4; ++r)
            qk[(size_t)(row0 + r) * LQK + col] = f2b(acc[i][j][r] + bv);
        } else if (bn0 < 2 * C_EMB) {   // k columns: swizzled within head
          #pragma unroll
          for (int r = 0; r < 4; ++r) {
            const int row = row0 + r;
            qk[(size_t)row * LQK + (col & ~127) + ((col & 127) ^ ((row & 7) << 3))] =
                f2b(acc[i][j][r] + bv);
          }
        } else {                        // v columns -> transposed+swizzled store
          const int c2 = col - 2 * C_EMB;           // h*128 + d
          const int bb = row0 >> 11;                // batch
          const int t0 = row0 & (T_SEQ - 1);
          const int vrow = (bb * NH + (c2 >> 7)) * HD + (c2 & 127);
          ushort4 p;
          p.x = f2b(acc[i][j][0] + bv); p.y = f2b(acc[i][j][1] + bv);
          p.z = f2b(acc[i][j][2] + bv); p.w = f2b(acc[i][j][3] + bv);
          *(ushort4*)(vt + (size_t)vrow * T_SEQ + (t0 ^ ((vrow & 7) << 3))) = p;  // stays in 64-tile
        }
      }
    }
  }
}

// ---------------------------------------------------------------------------
// Tier A 128-tile GEMM (m97 structure) — retained for the proj GEMM.
// ---------------------------------------------------------------------------
template <int MODE, typename OutT>
__global__ __launch_bounds__(256) void gemm_bt(const unsigned short* __restrict__ A, int lda,
                                               const unsigned short* __restrict__ Bt,
                                               const float* __restrict__ bias,
                                               OutT* __restrict__ C, int ldc,
                                               unsigned short* __restrict__ qk,
                                               unsigned short* __restrict__ vt,
                                               int N, int K) {
  __shared__ __align__(16) unsigned short As[128 * 32];
  __shared__ __align__(16) unsigned short Bs[128 * 32];
  const int tid = threadIdx.x;
  const int wave = tid >> 6, lane = tid & 63;
  const int wm = wave >> 1, wn = wave & 1;
  const int ln = lane & 15, lq = lane >> 4;
  const int bm0 = blockIdx.y * 128, bn0 = blockIdx.x * 128;

  f32x4 acc[4][4];
  #pragma unroll
  for (int i = 0; i < 4; ++i)
    #pragma unroll
    for (int j = 0; j < 4; ++j) acc[i][j] = (f32x4){0.f, 0.f, 0.f, 0.f};

  const unsigned short* Ag = A  + (size_t)(bm0 + wave * 32 + (lane >> 2)) * lda + (lane & 3) * 8;
  const unsigned short* Bg = Bt + (size_t)(bn0 + wave * 32 + (lane >> 2)) * K   + (lane & 3) * 8;
  unsigned short* Al = As + wave * 1024 + lane * 8;
  unsigned short* Bl = Bs + wave * 1024 + lane * 8;

  for (int k0 = 0; k0 < K; k0 += 32) {
    async_cp16(Ag + k0, Al);
    async_cp16(Ag + k0 + 16 * lda, Al + 512);
    async_cp16(Bg + k0, Bl);
    async_cp16(Bg + k0 + 16 * K, Bl + 512);
    __syncthreads();
    bf16x8 af[4], bfv[4];
    #pragma unroll
    for (int i = 0; i < 4; ++i) {
      af[i]  = *(const bf16x8*)(As + (wm * 64 + i * 16 + ln) * 32 + lq * 8);
      bfv[i] = *(const bf16x8*)(Bs + (wn * 64 + i * 16 + ln) * 32 + lq * 8);
    }
    #pragma unroll
    for (int i = 0; i < 4; ++i)
      #pragma unroll
      for (int j = 0; j < 4; ++j)
        acc[i][j] = __builtin_amdgcn_mfma_f32_16x16x32_bf16(af[i], bfv[j], acc[i][j], 0, 0, 0);
    __syncthreads();
  }
  gemm_epilogue<MODE, OutT>(acc, bias, C, ldc, qk, vt, bm0, bn0, wm, wn, ln, lq);
}

// ---------------------------------------------------------------------------
// 256x256 8-phase GEMM (m201 template, plain HIP port): C = A * Bt^T + bias.
//   BM=BN=256, BK=64, 512 threads = 8 waves (2M x 4N), per-wave out 128x64.
//   LDS 128 KiB: 2 dbuf x 2 halves x [128 rows x 64 k] x {A,B} bf16.
//   Stagger (r2): region lifetimes — buf-B frees after ph2, buf-A after
//   ph3 (reads rq=0 at ph1, rq=1 at ph3; B c01 at ph1, c23 at ph2). Staging:
//     ph3: B(ta,h0)+B(ta,h1)   ph4: A(ta,h0)+A(ta,h1)  VMC(8)
//     ph7: B(tb,h0)+B(tb,h1)   ph8: A(tb,h0)+A(tb,h1)  VMC(8)
//   Queue at ph4: [B(t1)4,A(t1)4 | B(ta)4,A(ta)4] -> vmcnt(8) drains t1.
//   Queue at ph8: [B(ta)4,A(ta)4 | B(tb)4,A(tb)4] -> drains ta (issued
//   ph3/ph4 = 4-5 phases of flight). Every load has >=4 phases (~1600cy).
//   Tail iteration re-stages current tiles (identical bytes -> benign).
// ---------------------------------------------------------------------------
#define BARRIER8 do { __builtin_amdgcn_s_barrier(); __builtin_amdgcn_sched_barrier(0); } while (0)
#define VMC8 asm volatile("s_waitcnt vmcnt(8)" ::: "memory")

#define STAGE_A8(t, h) do { \
    const unsigned short* g_ = Ag0 + (size_t)((h) * 128) * lda + (t) * 64; \
    unsigned short* l_ = ldsA + ((t) & 1) * 16384 + (h) * 8192 + tid * 8; \
    async_cp16(g_, l_); \
    async_cp16(g_ + (size_t)64 * lda, l_ + 4096); \
  } while (0)
#define STAGE_B8(t, h) do { \
    const unsigned short* g_ = Bg0 + (size_t)((h) * 128) * ldb + (t) * 64; \
    unsigned short* l_ = ldsB + ((t) & 1) * 16384 + (h) * 8192 + tid * 8; \
    async_cp16(g_, l_); \
    async_cp16(g_ + (size_t)64 * ldb, l_ + 4096); \
  } while (0)

#define LOADA8(ab, rq) do { \
    _Pragma("unroll") for (int rt_ = 0; rt_ < 4; ++rt_) { \
      af[rt_][0] = *(const bf16x8*)((ab) + (rq) * 4096 + rt_ * 1024 + kx0); \
      af[rt_][1] = *(const bf16x8*)((ab) + (rq) * 4096 + rt_ * 1024 + kx1); \
    } } while (0)
#define LOADB8(bb, cj0) do { \
    bv_[(cj0)][0]     = *(const bf16x8*)((bb) + (cj0) * 1024 + kx0); \
    bv_[(cj0)][1]     = *(const bf16x8*)((bb) + (cj0) * 1024 + kx1); \
    bv_[(cj0) + 1][0] = *(const bf16x8*)((bb) + ((cj0) + 1) * 1024 + kx0); \
    bv_[(cj0) + 1][1] = *(const bf16x8*)((bb) + ((cj0) + 1) * 1024 + kx1); \
  } while (0)
#define MFMAQ8(rq, cq) do { \
    __builtin_amdgcn_s_setprio(1); \
    _Pragma("unroll") for (int rt_ = 0; rt_ < 4; ++rt_) \
      _Pragma("unroll") for (int ct_ = 0; ct_ < 2; ++ct_) \
        _Pragma("unroll") for (int kk_ = 0; kk_ < 2; ++kk_) \
          acc[(rq) * 4 + rt_][(cq) * 2 + ct_] = __builtin_amdgcn_mfma_f32_16x16x32_bf16( \
              af[rt_][kk_], bv_[(cq) * 2 + ct_][kk_], acc[(rq) * 4 + rt_][(cq) * 2 + ct_], 0, 0, 0); \
    __builtin_amdgcn_s_setprio(0); \
  } while (0)

template <int MODE, typename OutT>
__global__ __launch_bounds__(512, 2) void gemm8_bt(
    const unsigned short* __restrict__ A, int lda,
    const unsigned short* __restrict__ Bt, int ldb,
    const float* __restrict__ bias,
    OutT* __restrict__ C, int ldc,
    unsigned short* __restrict__ qk, unsigned short* __restrict__ vt, int K) {
  __shared__ __align__(16) unsigned short lds8[65536];  // 128 KiB
  unsigned short* ldsA = lds8;
  unsigned short* ldsB = lds8 + 32768;

  const int tid = threadIdx.x;
  const int wave = tid >> 6, lane = tid & 63;
  const int wm = wave >> 2, wn = wave & 3;
  const int ln = lane & 15, lq = lane >> 4;

  const int nbx = gridDim.x;
  int bid = blockIdx.y * nbx + blockIdx.x;
  const int nwg = nbx * gridDim.y;
  if (!(nwg & 7)) bid = (bid & 7) * (nwg >> 3) + (bid >> 3);   // XCD swizzle (bijective: nwg%8==0)
  const int bm0 = (bid / nbx) * 256;
  const int bn0 = (bid % nbx) * 256;

  // staging addressing: thread covers rows (tid>>3) and (tid>>3)+64 of a half,
  // 16B slot (tid&7); pre-swizzled global k-offset = (slot ^ (row&7))*8 shorts.
  const int srow = tid >> 3;
  const int scol = ((tid & 7) ^ (srow & 7)) << 3;
  const unsigned short* Ag0 = A  + (size_t)(bm0 + srow) * lda + scol;
  const unsigned short* Bg0 = Bt + (size_t)(bn0 + srow) * ldb + scol;

  // compute-side swizzled k-offsets (shorts): (ko + lq*8) ^ ((ln&7)<<3)
  const int kx0 = (lq * 8) ^ ((ln & 7) << 3);
  const int kx1 = (32 + lq * 8) ^ ((ln & 7) << 3);
  const unsigned short* Ab0 = lds8 + wm * 8192 + ln * 64;
  const unsigned short* Bb0 = lds8 + 32768 + (wn >> 1) * 8192 + ((wn & 1) * 64 + ln) * 64;
  const unsigned short* Ab1 = Ab0 + 16384;
  const unsigned short* Bb1 = Bb0 + 16384;

  f32x4 acc[8][4];
  #pragma unroll
  for (int i = 0; i < 8; ++i)
    #pragma unroll
    for (int j = 0; j < 4; ++j) acc[i][j] = (f32x4){0.f, 0.f, 0.f, 0.f};
  bf16x8 af[4][2], bv_[4][2];

  // prologue: tiles 0 and 1 fully staged (16 loads); wait tile0 (oldest 8).
  STAGE_B8(0, 0); STAGE_B8(0, 1); STAGE_A8(0, 0); STAGE_A8(0, 1);
  STAGE_B8(1, 0); STAGE_B8(1, 1); STAGE_A8(1, 0); STAGE_A8(1, 1);
  VMC8;
  BARRIER8;

  const int NT = K >> 6, NI = NT >> 1;
  for (int i = 0; i < NI; ++i) {
    const int ta = (2 * i + 2 < NT) ? (2 * i + 2) : (2 * i);      // tail: restage (same bytes)
    const int tb = (2 * i + 3 < NT) ? (2 * i + 3) : (2 * i + 1);
    // ---- K-tile t0 (buf0)
    LOADA8(Ab0, 0); LOADB8(Bb0, 0);                         BARRIER8; MFMAQ8(0, 0); BARRIER8;  // ph1
    LOADB8(Bb0, 2);                                         BARRIER8; MFMAQ8(0, 1); BARRIER8;  // ph2
    LOADA8(Ab0, 1); STAGE_B8(ta, 0); STAGE_B8(ta, 1);       BARRIER8; MFMAQ8(1, 0); BARRIER8;  // ph3
    STAGE_A8(ta, 0); STAGE_A8(ta, 1); VMC8;                 BARRIER8; MFMAQ8(1, 1); BARRIER8;  // ph4
    // ---- K-tile t1 (buf1)
    LOADA8(Ab1, 0); LOADB8(Bb1, 0);                         BARRIER8; MFMAQ8(0, 0); BARRIER8;  // ph5
    LOADB8(Bb1, 2);                                         BARRIER8; MFMAQ8(0, 1); BARRIER8;  // ph6
    LOADA8(Ab1, 1); STAGE_B8(tb, 0); STAGE_B8(tb, 1);       BARRIER8; MFMAQ8(1, 0); BARRIER8;  // ph7
    STAGE_A8(tb, 0); STAGE_A8(tb, 1); VMC8;                 BARRIER8; MFMAQ8(1, 1); BARRIER8;  // ph8
  }

  // ---- epilogue: wave rows bm0+wm*128+ri*16+lq*4+r, cols bn0+wn*64+cj*16+ln
  #pragma unroll
  for (int ri = 0; ri < 8; ++ri) {
    const int row0 = bm0 + wm * 128 + ri * 16 + lq * 4;
    #pragma unroll
    for (int cj = 0; cj < 4; ++cj) {
      const int col = bn0 + wn * 64 + cj * 16 + ln;
      const float bvs = bias[col];
      if constexpr (MODE == 0) {
        #pragma unroll
        for (int r = 0; r < 4; ++r)
          store_out(&C[(size_t)(row0 + r) * ldc + col], acc[ri][cj][r] + bvs);
      } else {
        if (bn0 < C_EMB) {              // q cols: linear (256-tile never straddles)
          #pragma unroll
          for (int r = 0; r < 4; ++r)
            qk[(size_t)(row0 + r) * LQK + col] = f2b(acc[ri][cj][r] + bvs);
        } else if (bn0 < 2 * C_EMB) {   // k cols: swizzled within head
          #pragma unroll
          for (int r = 0; r < 4; ++r) {
            const int row = row0 + r;
            qk[(size_t)row * LQK + (col & ~127) + ((col & 127) ^ ((row & 7) << 3))] =
                f2b(acc[ri][cj][r] + bvs);
          }
        } else {                        // v cols -> transposed+swizzled store into vt
          const int c2 = col - 2 * C_EMB;
          const int bb = row0 >> 11;
          const int t0v = row0 & (T_SEQ - 1);
          const int vrow = (bb * NH + (c2 >> 7)) * HD + (c2 & 127);
          ushort4 p;
          p.x = f2b(acc[ri][cj][0] + bvs); p.y = f2b(acc[ri][cj][1] + bvs);
          p.z = f2b(acc[ri][cj][2] + bvs); p.w = f2b(acc[ri][cj][3] + bvs);
          *(ushort4*)(vt + (size_t)vrow * T_SEQ + (t0v ^ ((vrow & 7) << 3))) = p;
        }
      }
    }
  }
}

// ---------------------------------------------------------------------------
// Tier B GEMM fallback (validated round-2 structure).
// ---------------------------------------------------------------------------
template <int MODE, typename AT, typename OutT>
__global__ __launch_bounds__(256) void gemm_any(const AT* __restrict__ A, int lda,
                                                const float* __restrict__ B, int ldb,
                                                const float* __restrict__ bias,
                                                OutT* __restrict__ C, int ldc,
                                                unsigned short* __restrict__ qk,
                                                unsigned short* __restrict__ vt,
                                                int N, int K) {
  __shared__ __align__(16) unsigned short As[128 * 32];
  __shared__ __align__(16) unsigned short Bs[128 * 32];
  __shared__ __align__(16) float Bstage[32 * 132];

  const int tid = threadIdx.x;
  const int wave = tid >> 6, lane = tid & 63;
  const int wm = wave >> 1, wn = wave & 1;
  const int ln = lane & 15, lq = lane >> 4;
  const int bm0 = blockIdx.y * 128, bn0 = blockIdx.x * 128;

  f32x4 acc[4][4];
  #pragma unroll
  for (int i = 0; i < 4; ++i)
    #pragma unroll
    for (int j = 0; j < 4; ++j) acc[i][j] = (f32x4){0.f, 0.f, 0.f, 0.f};

  for (int k0 = 0; k0 < K; k0 += 32) {
    #pragma unroll
    for (int j = 0; j < 4; ++j) {
      const int item = tid + j * 256;
      const int m = item >> 3;
      const int kf = (item & 7) * 4;
      *(ushort4*)(As + m * 32 + kf) = load4_bf16(A + (size_t)(bm0 + m) * lda + k0 + kf);
    }
    #pragma unroll
    for (int j = 0; j < 4; ++j) {
      const int item = tid + j * 256;
      const int kr = item >> 5;
      const int nf = (item & 31) * 4;
      *(float4*)(Bstage + kr * 132 + nf) =
          *(const float4*)(B + (size_t)(k0 + kr) * ldb + bn0 + nf);
    }
    __syncthreads();
    #pragma unroll
    for (int j = 0; j < 4; ++j) {
      const int item = tid + j * 256;
      const int n = item >> 3;
      const int kq = item & 7;
      const int k = kq * 4;
      ushort4 h4;
      h4.x = f2b(Bstage[(k + 0) * 132 + n]);
      h4.y = f2b(Bstage[(k + 1) * 132 + n]);
      h4.z = f2b(Bstage[(k + 2) * 132 + n]);
      h4.w = f2b(Bstage[(k + 3) * 132 + n]);
      *(ushort4*)(Bs + n * 32 + (((kq >> 1) ^ (n & 3)) << 3) + ((kq & 1) << 2)) = h4;
    }
    __syncthreads();
    bf16x8 af[4], bfv[4];
    #pragma unroll
    for (int i = 0; i < 4; ++i) {
      af[i] = *(const bf16x8*)(As + (wm * 64 + i * 16 + ln) * 32 + lq * 8);
      const int n = wn * 64 + i * 16 + ln;
      bfv[i] = *(const bf16x8*)(Bs + n * 32 + ((lq ^ (n & 3)) << 3));
    }
    #pragma unroll
    for (int i = 0; i < 4; ++i)
      #pragma unroll
      for (int j = 0; j < 4; ++j)
        acc[i][j] = __builtin_amdgcn_mfma_f32_16x16x32_bf16(af[i], bfv[j], acc[i][j], 0, 0, 0);
    __syncthreads();
  }
  gemm_epilogue<MODE, OutT>(acc, bias, C, ldc, qk, vt, bm0, bn0, wm, wn, ln, lq);
}

// ---------------------------------------------------------------- prep (Tier A)
__global__ __launch_bounds__(256) void cast_x_bf16(const float4* __restrict__ in,
                                                   ushort4* __restrict__ out, int n4) {
  int i = blockIdx.x * 256 + threadIdx.x;
  if (i < n4) {
    float4 v = in[i];
    ushort4 o; o.x = f2b(v.x); o.y = f2b(v.y); o.z = f2b(v.z); o.w = f2b(v.w);
    out[i] = o;
  }
}

__global__ __launch_bounds__(256) void transpose_cast(const float* __restrict__ in,
                                                      unsigned short* __restrict__ out,
                                                      int R, int Cc) {
  __shared__ float t[32][33];
  const int bx = blockIdx.x * 32, by = blockIdx.y * 32;
  const int tx = threadIdx.x & 31, ty = threadIdx.x >> 5;
  #pragma unroll
  for (int j = 0; j < 32; j += 8)
    t[ty + j][tx] = in[(size_t)(by + ty + j) * Cc + bx + tx];
  __syncthreads();
  #pragma unroll
  for (int j = 0; j < 32; j += 8)
    out[(size_t)(bx + ty + j) * R + by + tx] = f2b(t[tx][ty + j]);
}

// ---------------------------------------------------------------------------
// Flash attention: transposed-S, max-free softmax, 8-wave (512-thread) blocks.
// r2: double-buffered K/V tiles staged via global_load_lds (linear LDS, the
// XOR swizzle is baked into the global K/V layout by the GEMM epilogues);
// counted vmcnt(4) + raw s_barrier so each tile's 4 loads/thread get a full
// iteration of compute (~1500cy) to land; setprio around MFMA clusters.
// Iteration kb: [vmcnt(4); barrier] -> compute buf[kb&1] -> [barrier] ->
// stage(min(kb+2,kbmax) -> buf[kb&1]).  Queue at head of kb:
// [tile kb (4), tile kb+1 (4)] -> vmcnt(4) drains tile kb exactly. Clamped
// tail restage keeps the queue depth invariant (redundant bytes, unread).
// ---------------------------------------------------------------------------
__global__ __launch_bounds__(512, 4) void attn_st(unsigned short* __restrict__ qk,
                                                  const unsigned short* __restrict__ vt) {
  // 2 buffers x (K [64][128] + V^T [128][64]) = 2 x 16384 shorts = 64 KiB.
  // Epilogue reuses [0..17408) as Os[128][136].
  __shared__ __align__(16) unsigned short smem[32768];

  const int tid = threadIdx.x;
  const int w = tid >> 6, lane = tid & 63;
  const int ln = lane & 15, lq = lane >> 4;
  const int b = blockIdx.z, h = blockIdx.y;
  const int j = (b == 0) ? (15 - (int)blockIdx.x) : (int)blockIdx.x;
  const int qb0 = j * 128;
  const float EXPSC = 0.08838834764831845f * 1.4426950408889634f;
  const int xsw = (ln & 7) << 3;   // read-side XOR (row&7 == ln&7 for both K and V reads)

  // Q fragments (B-operand: n=ln=query, k=lq*8..) straight from global, once
  const int wq0 = qb0 + w * 16;
  const int qg = wq0 + ln;
  const unsigned short* Qp = qk + (size_t)(b * T_SEQ + qg) * LQK + h * HD + lq * 8;
  bf16x8 bq[4];
  #pragma unroll
  for (int ks = 0; ks < 4; ++ks) bq[ks] = *(const bf16x8*)(Qp + ks * 32);

  // staging bases (global layouts pre-swizzled -> linear row copies)
  const unsigned short* Kg = qk + (size_t)(b * T_SEQ) * LQK + C_EMB + h * HD;
  const unsigned short* Vg = vt + ((size_t)(b * NH + h) * HD) * T_SEQ;
  const int krow = tid >> 4, kc16 = (tid & 15) * 8;   // K: 32 rows/chunk x 16 slots
  const int vrow = tid >> 3, vc16 = (tid & 7) * 8;    // V: 64 rows/chunk x 8 slots

  f32x4 ot[8];  // O^T accum: regs = d = dt*16+lq*4+r, col = query ln
  #pragma unroll
  for (int dt = 0; dt < 8; ++dt) ot[dt] = (f32x4){0.f, 0.f, 0.f, 0.f};
  float l_i = 0.f;

  // prologue: stage tiles 0 (buf0) and 1 (buf1): 4 cp16/thread each
  {
    unsigned short* b0 = smem;
    async_cp16(Kg + (size_t)(0 * 64 + krow) * LQK + kc16,        b0 + tid * 8);
    async_cp16(Kg + (size_t)(0 * 64 + krow + 32) * LQK + kc16,   b0 + 4096 + tid * 8);
    async_cp16(Vg + (size_t)vrow * T_SEQ + 0 * 64 + vc16,        b0 + 8192 + tid * 8);
    async_cp16(Vg + (size_t)(vrow + 64) * T_SEQ + 0 * 64 + vc16, b0 + 12288 + tid * 8);
    unsigned short* b1 = smem + 16384;
    async_cp16(Kg + (size_t)(1 * 64 + krow) * LQK + kc16,        b1 + tid * 8);
    async_cp16(Kg + (size_t)(1 * 64 + krow + 32) * LQK + kc16,   b1 + 4096 + tid * 8);
    async_cp16(Vg + (size_t)vrow * T_SEQ + 1 * 64 + vc16,        b1 + 8192 + tid * 8);
    async_cp16(Vg + (size_t)(vrow + 64) * T_SEQ + 1 * 64 + vc16, b1 + 12288 + tid * 8);
  }

  const int kbmax = 2 * j + 1;
  for (int kb = 0; kb <= kbmax; ++kb) {
    asm volatile("s_waitcnt vmcnt(4)" ::: "memory");  // tile kb landed (tile kb+1 in flight)
    __builtin_amdgcn_s_barrier();
    __builtin_amdgcn_sched_barrier(0);
    const unsigned short* Ksb = smem + (kb & 1) * 16384;
    const unsigned short* Vsb = Ksb + 8192;

    if (kb * 64 <= wq0 + 15) {            // wave has unmasked work this block
      const bool diag = (kb * 64 + 63 > wq0);

      // ---- S^T = K Q^T
      f32x4 st[4];
      __builtin_amdgcn_s_setprio(1);
      #pragma unroll
      for (int kt = 0; kt < 4; ++kt) {
        st[kt] = (f32x4){0.f, 0.f, 0.f, 0.f};
        #pragma unroll
        for (int ks = 0; ks < 4; ++ks) {
          bf16x8 ak = *(const bf16x8*)(Ksb + (kt * 16 + ln) * 128 + ((ks * 32 + lq * 8) ^ xsw));
          st[kt] = __builtin_amdgcn_mfma_f32_16x16x32_bf16(ak, bq[ks], st[kt], 0, 0, 0);
        }
      }
      __builtin_amdgcn_s_setprio(0);

      // ---- max-free softmax: p = exp2(s*EXPSC); zero masked; accumulate l
      short4v pf[4];
      #pragma unroll
      for (int kt = 0; kt < 4; ++kt)
        #pragma unroll
        for (int r = 0; r < 4; ++r) {
          float p = __builtin_exp2f(st[kt][r] * EXPSC);
          if (diag && (kb * 64 + kt * 16 + lq * 4 + r > qg)) p = 0.f;
          l_i += p;
          pf[kt][r] = (short)f2b(p);
        }

      // ---- O^T += V^T P^T : K=16 MFMA, P straight from registers
      __builtin_amdgcn_s_setprio(1);
      #pragma unroll
      for (int kt = 0; kt < 4; ++kt)
        #pragma unroll
        for (int dt = 0; dt < 8; ++dt) {
          short4v av = *(const short4v*)(Vsb + (dt * 16 + ln) * 64 + ((kt * 16 + lq * 4) ^ xsw));
          ot[dt] = __builtin_amdgcn_mfma_f32_16x16x16bf16_1k(av, pf[kt], ot[dt], 0, 0, 0);
        }
      __builtin_amdgcn_s_setprio(0);
    }

    __builtin_amdgcn_s_barrier();        // all waves done reading buf[kb&1]
    __builtin_amdgcn_sched_barrier(0);
    const int kn = (kb + 2 <= kbmax) ? (kb + 2) : kbmax;  // clamp keeps queue depth
    unsigned short* dst = smem + (kb & 1) * 16384;
    async_cp16(Kg + (size_t)(kn * 64 + krow) * LQK + kc16,        dst + tid * 8);
    async_cp16(Kg + (size_t)(kn * 64 + krow + 32) * LQK + kc16,   dst + 4096 + tid * 8);
    async_cp16(Vg + (size_t)vrow * T_SEQ + kn * 64 + vc16,        dst + 8192 + tid * 8);
    async_cp16(Vg + (size_t)(vrow + 64) * T_SEQ + kn * 64 + vc16, dst + 12288 + tid * 8);
  }

  // ---- final l reduction across the 4 partner lanes (once)
  l_i += __shfl_xor(l_i, 16);
  l_i += __shfl_xor(l_i, 32);
  const float inv = 1.f / l_i;

  // ---- epilogue: O^T -> O via LDS (smem as Os[128][136]), coalesced store.
  // Drain in-flight staging before reusing smem.
  asm volatile("s_waitcnt vmcnt(0)" ::: "memory");
  __syncthreads();
  #pragma unroll
  for (int dt = 0; dt < 8; ++dt) {
    ushort4 p4;
    p4.x = f2b(ot[dt][0] * inv); p4.y = f2b(ot[dt][1] * inv);
    p4.z = f2b(ot[dt][2] * inv); p4.w = f2b(ot[dt][3] * inv);
    *(ushort4*)(smem + (w * 16 + ln) * 136 + dt * 16 + lq * 4) = p4;
  }
  __syncthreads();
  #pragma unroll
  for (int jj = 0; jj < 4; ++jj) {        // 128 rows x 16 uint4 = 2048 items
    const int s = tid + jj * 512;
    const int row = s >> 4, c8 = s & 15;
    *(uint4*)(qk + (size_t)(b * T_SEQ + qb0 + row) * LQK + h * HD + c8 * 8) =
        *(const uint4*)(smem + row * 136 + c8 * 8);
  }
}

// ---------------------------------------------------------------- launch
extern "C" void kernel_launch(void* const* d_in, const int* in_sizes, int n_in,
                              void* d_out, int out_size, void* d_ws, size_t ws_size,
                              hipStream_t stream) {
  (void)in_sizes; (void)n_in; (void)out_size;
  const float* x      = (const float*)d_in[0];
  const float* W_attn = (const float*)d_in[1];
  const float* b_attn = (const float*)d_in[2];
  const float* W_proj = (const float*)d_in[3];
  const float* b_proj = (const float*)d_in[4];
  float* out = (float*)d_out;

  char* ws = (char*)d_ws;
  unsigned short* qk = (unsigned short*)(ws);                  // 32 MiB [4096][4096]
  unsigned short* vt = (unsigned short*)(ws + 33554432);       // 16 MiB [B*NH*HD][T]
  unsigned short* xb  = (unsigned short*)(ws + 50331648);      // 16 MiB x bf16
  unsigned short* WaT = (unsigned short*)(ws + 67108864);      // 24 MiB W_attn^T bf16
  unsigned short* WpT = (unsigned short*)(ws + 92274688);      // 8  MiB W_proj^T bf16
  const bool tierA = (ws_size >= 100663296);                   // 96 MiB

  if (tierA) {
    const int n_x = M_ROWS * C_EMB;
    cast_x_bf16<<<n_x / 4 / 256, 256, 0, stream>>>((const float4*)x, (ushort4*)xb, n_x / 4);
    transpose_cast<<<dim3(N_QKV / 32, C_EMB / 32), 256, 0, stream>>>(W_attn, WaT, C_EMB, N_QKV);
    transpose_cast<<<dim3(C_EMB / 32, C_EMB / 32), 256, 0, stream>>>(W_proj, WpT, C_EMB, C_EMB);
    gemm8_bt<1, unsigned short><<<dim3(N_QKV / 256, M_ROWS / 256), 512, 0, stream>>>(
        xb, C_EMB, WaT, C_EMB, b_attn, (unsigned short*)nullptr, 0, qk, vt, C_EMB);
  } else {
    gemm_any<1, float, unsigned short><<<dim3(N_QKV / 128, M_ROWS / 128), 256, 0, stream>>>(
        x, C_EMB, W_attn, N_QKV, b_attn, (unsigned short*)nullptr, 0, qk, vt, N_QKV, C_EMB);
  }

  attn_st<<<dim3(16, NH, B_SZ), 512, 0, stream>>>(qk, vt);

  if (tierA) {
    gemm_bt<0, float><<<dim3(C_EMB / 128, M_ROWS / 128), 256, 0, stream>>>(
        qk, LQK, WpT, b_proj, out, C_EMB, nullptr, nullptr, C_EMB, C_EMB);
  } else {
    gemm_any<0, unsigned short, float><<<dim3(C_EMB / 128, M_ROWS / 128), 256, 0, stream>>>(
        qk, LQK, W_proj, C_EMB, b_proj, out, C_EMB, nullptr, nullptr, C_EMB, C_EMB);
  }
}

// Round 4
// 390.663 us; speedup vs baseline: 1.0656x; 1.0159x over previous
//
#include <hip/hip_runtime.h>
#include <hip/hip_bf16.h>

typedef __bf16 bf16x8 __attribute__((ext_vector_type(8)));
typedef float  f32x4  __attribute__((ext_vector_type(4)));
typedef short  short4v __attribute__((ext_vector_type(4)));

#define B_SZ   2
#define T_SEQ  2048
#define C_EMB  2048
#define NH     16
#define HD     128
#define M_ROWS (B_SZ * T_SEQ)   /* 4096 */
#define N_QKV  (3 * C_EMB)      /* 6144 */
#define LQK    (2 * C_EMB)      /* 4096: qk buffer row length (q|k columns) */

// Global K layout (qk cols [2048,4096)): within-head col c stored at
//   c ^ ((t&7)<<3)   (t = key row). Global V^T layout (vt): within each
// 64-key tile, key col t stored at t ^ ((d&7)<<3) (d = vt row & 127).
// Both swizzles let attn stage tiles LINEARLY via global_load_lds and read
// conflict-free with the same XOR (both-sides involution).

static __device__ __forceinline__ unsigned short f2b(float f) {
  union { __hip_bfloat16 h; unsigned short u; } cv;
  cv.h = __float2bfloat16(f);
  return cv.u;
}
static __device__ __forceinline__ void store_out(float* p, float v) { *p = v; }
static __device__ __forceinline__ void store_out(unsigned short* p, float v) { *p = f2b(v); }

static __device__ __forceinline__ ushort4 load4_bf16(const float* p) {
  float4 v = *(const float4*)p;
  ushort4 o; o.x = f2b(v.x); o.y = f2b(v.y); o.z = f2b(v.z); o.w = f2b(v.w);
  return o;
}
static __device__ __forceinline__ ushort4 load4_bf16(const unsigned short* p) {
  return *(const ushort4*)p;
}

// async global->LDS, 16B/lane; LDS dest must be wave-uniform base + lane*16
static __device__ __forceinline__ void async_cp16(const unsigned short* g, unsigned short* l) {
  __builtin_amdgcn_global_load_lds((__attribute__((address_space(1))) void*)(g),
                                   (__attribute__((address_space(3))) void*)(l), 16, 0, 0);
}

// ---------------------------------------------------------------------------
// Shared epilogue helper for the 128-tile kernels. MODE 0: C = acc + bias.
// MODE 1 (qkv split): q cols linear; k cols swizzled; v cols -> vt swizzled.
// ---------------------------------------------------------------------------
template <int MODE, typename OutT>
static __device__ __forceinline__ void gemm_epilogue(
    f32x4 (&acc)[4][4], const float* __restrict__ bias,
    OutT* __restrict__ C, int ldc,
    unsigned short* __restrict__ qk, unsigned short* __restrict__ vt,
    int bm0, int bn0, int wm, int wn, int ln, int lq) {
  #pragma unroll
  for (int i = 0; i < 4; ++i) {
    const int row0 = bm0 + wm * 64 + i * 16 + lq * 4;
    #pragma unroll
    for (int j = 0; j < 4; ++j) {
      const int col = bn0 + wn * 64 + j * 16 + ln;
      const float bv = bias[col];
      if constexpr (MODE == 0) {
        #pragma unroll
        for (int r = 0; r < 4; ++r)
          store_out(&C[(size_t)(row0 + r) * ldc + col], acc[i][j][r] + bv);
      } else {
        if (bn0 < C_EMB) {              // q columns: linear
          #pragma unroll
          for (int r = 0; r < 4; ++r)
            qk[(size_t)(row0 + r) * LQK + col] = f2b(acc[i][j][r] + bv);
        } else if (bn0 < 2 * C_EMB) {   // k columns: swizzled within head
          #pragma unroll
          for (int r = 0; r < 4; ++r) {
            const int row = row0 + r;
            qk[(size_t)row * LQK + (col & ~127) + ((col & 127) ^ ((row & 7) << 3))] =
                f2b(acc[i][j][r] + bv);
          }
        } else {                        // v columns -> transposed+swizzled store
          const int c2 = col - 2 * C_EMB;           // h*128 + d
          const int bb = row0 >> 11;                // batch
          const int t0 = row0 & (T_SEQ - 1);
          const int vrow = (bb * NH + (c2 >> 7)) * HD + (c2 & 127);
          ushort4 p;
          p.x = f2b(acc[i][j][0] + bv); p.y = f2b(acc[i][j][1] + bv);
          p.z = f2b(acc[i][j][2] + bv); p.w = f2b(acc[i][j][3] + bv);
          *(ushort4*)(vt + (size_t)vrow * T_SEQ + (t0 ^ ((vrow & 7) << 3))) = p;  // stays in 64-tile
        }
      }
    }
  }
}

// ---------------------------------------------------------------------------
// Tier A 128-tile GEMM (m97 structure) — retained for the proj GEMM.
// ---------------------------------------------------------------------------
template <int MODE, typename OutT>
__global__ __launch_bounds__(256) void gemm_bt(const unsigned short* __restrict__ A, int lda,
                                               const unsigned short* __restrict__ Bt,
                                               const float* __restrict__ bias,
                                               OutT* __restrict__ C, int ldc,
                                               unsigned short* __restrict__ qk,
                                               unsigned short* __restrict__ vt,
                                               int N, int K) {
  __shared__ __align__(16) unsigned short As[128 * 32];
  __shared__ __align__(16) unsigned short Bs[128 * 32];
  const int tid = threadIdx.x;
  const int wave = tid >> 6, lane = tid & 63;
  const int wm = wave >> 1, wn = wave & 1;
  const int ln = lane & 15, lq = lane >> 4;
  const int bm0 = blockIdx.y * 128, bn0 = blockIdx.x * 128;

  f32x4 acc[4][4];
  #pragma unroll
  for (int i = 0; i < 4; ++i)
    #pragma unroll
    for (int j = 0; j < 4; ++j) acc[i][j] = (f32x4){0.f, 0.f, 0.f, 0.f};

  const unsigned short* Ag = A  + (size_t)(bm0 + wave * 32 + (lane >> 2)) * lda + (lane & 3) * 8;
  const unsigned short* Bg = Bt + (size_t)(bn0 + wave * 32 + (lane >> 2)) * K   + (lane & 3) * 8;
  unsigned short* Al = As + wave * 1024 + lane * 8;
  unsigned short* Bl = Bs + wave * 1024 + lane * 8;

  for (int k0 = 0; k0 < K; k0 += 32) {
    async_cp16(Ag + k0, Al);
    async_cp16(Ag + k0 + 16 * lda, Al + 512);
    async_cp16(Bg + k0, Bl);
    async_cp16(Bg + k0 + 16 * K, Bl + 512);
    __syncthreads();
    bf16x8 af[4], bfv[4];
    #pragma unroll
    for (int i = 0; i < 4; ++i) {
      af[i]  = *(const bf16x8*)(As + (wm * 64 + i * 16 + ln) * 32 + lq * 8);
      bfv[i] = *(const bf16x8*)(Bs + (wn * 64 + i * 16 + ln) * 32 + lq * 8);
    }
    #pragma unroll
    for (int i = 0; i < 4; ++i)
      #pragma unroll
      for (int j = 0; j < 4; ++j)
        acc[i][j] = __builtin_amdgcn_mfma_f32_16x16x32_bf16(af[i], bfv[j], acc[i][j], 0, 0, 0);
    __syncthreads();
  }
  gemm_epilogue<MODE, OutT>(acc, bias, C, ldc, qk, vt, bm0, bn0, wm, wn, ln, lq);
}

// ---------------------------------------------------------------------------
// 256x256 8-phase GEMM (m201 template, plain HIP port): C = A * Bt^T + bias.
//   BM=BN=256, BK=64, 512 threads = 8 waves (2M x 4N), per-wave out 128x64.
//   LDS 128 KiB: 2 dbuf x 2 halves x [128 rows x 64 k] x {A,B} bf16.
//
//   r4 schedule — derived from TRUE region lifetimes. Reads per buffer's
//   4-phase window (A: rq0@ph_a, rq1@ph_a+2 cover BOTH h-regions since wm
//   splits rows 0-127/128-255; B: c01@ph_b, c23@ph_b+1 likewise):
//     buf0-B frees after ph2, buf0-A after ph3, buf1-B after ph6, buf1-A ph7.
//   Earliest-legal staging, drains only at ph4/ph8 with vmcnt(6)
//   (= template's 2 loads x 3 half-tiles):
//     ph3: B(ta,h0)+B(ta,h1)  ph4: A(ta,h0), VMC6  ph5: A(ta,h1)
//     ph7: B(tb,h0)+B(tb,h1)  ph8: A(tb,h0), VMC6  ph1: A(t1,h1)
//   Queue at ph4: [B(t1)4, A(t1,h0)2 (prev ph7/8), A(t1,h1)2 (ph1) |
//     B(ta)4, A(ta,h0)2] -> vmcnt(6) drains buf1 exactly; drained flights
//     3-5 phases. Symmetric at ph8. Min flight 3 phases (was 2).
//   Tail iteration re-stages current tiles (identical bytes -> benign).
// ---------------------------------------------------------------------------
#define BARRIER8 do { __builtin_amdgcn_s_barrier(); __builtin_amdgcn_sched_barrier(0); } while (0)
#define VMC6 asm volatile("s_waitcnt vmcnt(6)" ::: "memory")

#define STAGE_A8(t, h) do { \
    const unsigned short* g_ = Ag0 + (size_t)((h) * 128) * lda + (t) * 64; \
    unsigned short* l_ = ldsA + ((t) & 1) * 16384 + (h) * 8192 + tid * 8; \
    async_cp16(g_, l_); \
    async_cp16(g_ + (size_t)64 * lda, l_ + 4096); \
  } while (0)
#define STAGE_B8(t, h) do { \
    const unsigned short* g_ = Bg0 + (size_t)((h) * 128) * ldb + (t) * 64; \
    unsigned short* l_ = ldsB + ((t) & 1) * 16384 + (h) * 8192 + tid * 8; \
    async_cp16(g_, l_); \
    async_cp16(g_ + (size_t)64 * ldb, l_ + 4096); \
  } while (0)

#define LOADA8(ab, rq) do { \
    _Pragma("unroll") for (int rt_ = 0; rt_ < 4; ++rt_) { \
      af[rt_][0] = *(const bf16x8*)((ab) + (rq) * 4096 + rt_ * 1024 + kx0); \
      af[rt_][1] = *(const bf16x8*)((ab) + (rq) * 4096 + rt_ * 1024 + kx1); \
    } } while (0)
#define LOADB8(bb, cj0) do { \
    bv_[(cj0)][0]     = *(const bf16x8*)((bb) + (cj0) * 1024 + kx0); \
    bv_[(cj0)][1]     = *(const bf16x8*)((bb) + (cj0) * 1024 + kx1); \
    bv_[(cj0) + 1][0] = *(const bf16x8*)((bb) + ((cj0) + 1) * 1024 + kx0); \
    bv_[(cj0) + 1][1] = *(const bf16x8*)((bb) + ((cj0) + 1) * 1024 + kx1); \
  } while (0)
#define MFMAQ8(rq, cq) do { \
    __builtin_amdgcn_s_setprio(1); \
    _Pragma("unroll") for (int rt_ = 0; rt_ < 4; ++rt_) \
      _Pragma("unroll") for (int ct_ = 0; ct_ < 2; ++ct_) \
        _Pragma("unroll") for (int kk_ = 0; kk_ < 2; ++kk_) \
          acc[(rq) * 4 + rt_][(cq) * 2 + ct_] = __builtin_amdgcn_mfma_f32_16x16x32_bf16( \
              af[rt_][kk_], bv_[(cq) * 2 + ct_][kk_], acc[(rq) * 4 + rt_][(cq) * 2 + ct_], 0, 0, 0); \
    __builtin_amdgcn_s_setprio(0); \
  } while (0)

template <int MODE, typename OutT>
__global__ __launch_bounds__(512, 2) void gemm8_bt(
    const unsigned short* __restrict__ A, int lda,
    const unsigned short* __restrict__ Bt, int ldb,
    const float* __restrict__ bias,
    OutT* __restrict__ C, int ldc,
    unsigned short* __restrict__ qk, unsigned short* __restrict__ vt, int K) {
  __shared__ __align__(16) unsigned short lds8[65536];  // 128 KiB
  unsigned short* ldsA = lds8;
  unsigned short* ldsB = lds8 + 32768;

  const int tid = threadIdx.x;
  const int wave = tid >> 6, lane = tid & 63;
  const int wm = wave >> 2, wn = wave & 3;
  const int ln = lane & 15, lq = lane >> 4;

  const int nbx = gridDim.x;
  int bid = blockIdx.y * nbx + blockIdx.x;
  const int nwg = nbx * gridDim.y;
  if (!(nwg & 7)) bid = (bid & 7) * (nwg >> 3) + (bid >> 3);   // XCD swizzle (bijective: nwg%8==0)
  const int bm0 = (bid / nbx) * 256;
  const int bn0 = (bid % nbx) * 256;

  // staging addressing: thread covers rows (tid>>3) and (tid>>3)+64 of a half,
  // 16B slot (tid&7); pre-swizzled global k-offset = (slot ^ (row&7))*8 shorts.
  const int srow = tid >> 3;
  const int scol = ((tid & 7) ^ (srow & 7)) << 3;
  const unsigned short* Ag0 = A  + (size_t)(bm0 + srow) * lda + scol;
  const unsigned short* Bg0 = Bt + (size_t)(bn0 + srow) * ldb + scol;

  // compute-side swizzled k-offsets (shorts): (ko + lq*8) ^ ((ln&7)<<3)
  const int kx0 = (lq * 8) ^ ((ln & 7) << 3);
  const int kx1 = (32 + lq * 8) ^ ((ln & 7) << 3);
  const unsigned short* Ab0 = lds8 + wm * 8192 + ln * 64;
  const unsigned short* Bb0 = lds8 + 32768 + (wn >> 1) * 8192 + ((wn & 1) * 64 + ln) * 64;
  const unsigned short* Ab1 = Ab0 + 16384;
  const unsigned short* Bb1 = Bb0 + 16384;

  f32x4 acc[8][4];
  #pragma unroll
  for (int i = 0; i < 8; ++i)
    #pragma unroll
    for (int j = 0; j < 4; ++j) acc[i][j] = (f32x4){0.f, 0.f, 0.f, 0.f};
  bf16x8 af[4][2], bv_[4][2];

  // prologue: replicate steady-state ph1 entry: buf0 landed; in flight =
  // [B(t1)x4, A(t1,h0)x2] = 6. Issue t0 fully (8), then B(t1) (4), A(t1,h0)
  // (2) -> 14 outstanding, VMC6 drains t0's 8.
  STAGE_B8(0, 0); STAGE_B8(0, 1); STAGE_A8(0, 0); STAGE_A8(0, 1);
  STAGE_B8(1, 0); STAGE_B8(1, 1); STAGE_A8(1, 0);
  VMC6;
  BARRIER8;

  const int NT = K >> 6, NI = NT >> 1;
  for (int i = 0; i < NI; ++i) {
    const int t1 = 2 * i + 1;
    const int ta = (2 * i + 2 < NT) ? (2 * i + 2) : (2 * i);      // tail: restage (same bytes)
    const int tb = (2 * i + 3 < NT) ? (2 * i + 3) : (2 * i + 1);
    // ---- K-tile t0 (buf0)
    LOADA8(Ab0, 0); LOADB8(Bb0, 0); STAGE_A8(t1, 1);        BARRIER8; MFMAQ8(0, 0); BARRIER8;  // ph1
    LOADB8(Bb0, 2);                                         BARRIER8; MFMAQ8(0, 1); BARRIER8;  // ph2
    LOADA8(Ab0, 1); STAGE_B8(ta, 0); STAGE_B8(ta, 1);       BARRIER8; MFMAQ8(1, 0); BARRIER8;  // ph3
    STAGE_A8(ta, 0); VMC6;                                  BARRIER8; MFMAQ8(1, 1); BARRIER8;  // ph4
    // ---- K-tile t1 (buf1)
    LOADA8(Ab1, 0); LOADB8(Bb1, 0); STAGE_A8(ta, 1);        BARRIER8; MFMAQ8(0, 0); BARRIER8;  // ph5
    LOADB8(Bb1, 2);                                         BARRIER8; MFMAQ8(0, 1); BARRIER8;  // ph6
    LOADA8(Ab1, 1); STAGE_B8(tb, 0); STAGE_B8(tb, 1);       BARRIER8; MFMAQ8(1, 0); BARRIER8;  // ph7
    STAGE_A8(tb, 0); VMC6;                                  BARRIER8; MFMAQ8(1, 1); BARRIER8;  // ph8
  }

  // ---- epilogue: wave rows bm0+wm*128+ri*16+lq*4+r, cols bn0+wn*64+cj*16+ln
  #pragma unroll
  for (int ri = 0; ri < 8; ++ri) {
    const int row0 = bm0 + wm * 128 + ri * 16 + lq * 4;
    #pragma unroll
    for (int cj = 0; cj < 4; ++cj) {
      const int col = bn0 + wn * 64 + cj * 16 + ln;
      const float bvs = bias[col];
      if constexpr (MODE == 0) {
        #pragma unroll
        for (int r = 0; r < 4; ++r)
          store_out(&C[(size_t)(row0 + r) * ldc + col], acc[ri][cj][r] + bvs);
      } else {
        if (bn0 < C_EMB) {              // q cols: linear (256-tile never straddles)
          #pragma unroll
          for (int r = 0; r < 4; ++r)
            qk[(size_t)(row0 + r) * LQK + col] = f2b(acc[ri][cj][r] + bvs);
        } else if (bn0 < 2 * C_EMB) {   // k cols: swizzled within head
          #pragma unroll
          for (int r = 0; r < 4; ++r) {
            const int row = row0 + r;
            qk[(size_t)row * LQK + (col & ~127) + ((col & 127) ^ ((row & 7) << 3))] =
                f2b(acc[ri][cj][r] + bvs);
          }
        } else {                        // v cols -> transposed+swizzled store into vt
          const int c2 = col - 2 * C_EMB;
          const int bb = row0 >> 11;
          const int t0v = row0 & (T_SEQ - 1);
          const int vrow = (bb * NH + (c2 >> 7)) * HD + (c2 & 127);
          ushort4 p;
          p.x = f2b(acc[ri][cj][0] + bvs); p.y = f2b(acc[ri][cj][1] + bvs);
          p.z = f2b(acc[ri][cj][2] + bvs); p.w = f2b(acc[ri][cj][3] + bvs);
          *(ushort4*)(vt + (size_t)vrow * T_SEQ + (t0v ^ ((vrow & 7) << 3))) = p;
        }
      }
    }
  }
}

// ---------------------------------------------------------------------------
// Tier B GEMM fallback (validated round-2 structure).
// ---------------------------------------------------------------------------
template <int MODE, typename AT, typename OutT>
__global__ __launch_bounds__(256) void gemm_any(const AT* __restrict__ A, int lda,
                                                const float* __restrict__ B, int ldb,
                                                const float* __restrict__ bias,
                                                OutT* __restrict__ C, int ldc,
                                                unsigned short* __restrict__ qk,
                                                unsigned short* __restrict__ vt,
                                                int N, int K) {
  __shared__ __align__(16) unsigned short As[128 * 32];
  __shared__ __align__(16) unsigned short Bs[128 * 32];
  __shared__ __align__(16) float Bstage[32 * 132];

  const int tid = threadIdx.x;
  const int wave = tid >> 6, lane = tid & 63;
  const int wm = wave >> 1, wn = wave & 1;
  const int ln = lane & 15, lq = lane >> 4;
  const int bm0 = blockIdx.y * 128, bn0 = blockIdx.x * 128;

  f32x4 acc[4][4];
  #pragma unroll
  for (int i = 0; i < 4; ++i)
    #pragma unroll
    for (int j = 0; j < 4; ++j) acc[i][j] = (f32x4){0.f, 0.f, 0.f, 0.f};

  for (int k0 = 0; k0 < K; k0 += 32) {
    #pragma unroll
    for (int j = 0; j < 4; ++j) {
      const int item = tid + j * 256;
      const int m = item >> 3;
      const int kf = (item & 7) * 4;
      *(ushort4*)(As + m * 32 + kf) = load4_bf16(A + (size_t)(bm0 + m) * lda + k0 + kf);
    }
    #pragma unroll
    for (int j = 0; j < 4; ++j) {
      const int item = tid + j * 256;
      const int kr = item >> 5;
      const int nf = (item & 31) * 4;
      *(float4*)(Bstage + kr * 132 + nf) =
          *(const float4*)(B + (size_t)(k0 + kr) * ldb + bn0 + nf);
    }
    __syncthreads();
    #pragma unroll
    for (int j = 0; j < 4; ++j) {
      const int item = tid + j * 256;
      const int n = item >> 3;
      const int kq = item & 7;
      const int k = kq * 4;
      ushort4 h4;
      h4.x = f2b(Bstage[(k + 0) * 132 + n]);
      h4.y = f2b(Bstage[(k + 1) * 132 + n]);
      h4.z = f2b(Bstage[(k + 2) * 132 + n]);
      h4.w = f2b(Bstage[(k + 3) * 132 + n]);
      *(ushort4*)(Bs + n * 32 + (((kq >> 1) ^ (n & 3)) << 3) + ((kq & 1) << 2)) = h4;
    }
    __syncthreads();
    bf16x8 af[4], bfv[4];
    #pragma unroll
    for (int i = 0; i < 4; ++i) {
      af[i] = *(const bf16x8*)(As + (wm * 64 + i * 16 + ln) * 32 + lq * 8);
      const int n = wn * 64 + i * 16 + ln;
      bfv[i] = *(const bf16x8*)(Bs + n * 32 + ((lq ^ (n & 3)) << 3));
    }
    #pragma unroll
    for (int i = 0; i < 4; ++i)
      #pragma unroll
      for (int j = 0; j < 4; ++j)
        acc[i][j] = __builtin_amdgcn_mfma_f32_16x16x32_bf16(af[i], bfv[j], acc[i][j], 0, 0, 0);
    __syncthreads();
  }
  gemm_epilogue<MODE, OutT>(acc, bias, C, ldc, qk, vt, bm0, bn0, wm, wn, ln, lq);
}

// ---------------------------------------------------------------- prep (Tier A)
__global__ __launch_bounds__(256) void cast_x_bf16(const float4* __restrict__ in,
                                                   ushort4* __restrict__ out, int n4) {
  int i = blockIdx.x * 256 + threadIdx.x;
  if (i < n4) {
    float4 v = in[i];
    ushort4 o; o.x = f2b(v.x); o.y = f2b(v.y); o.z = f2b(v.z); o.w = f2b(v.w);
    out[i] = o;
  }
}

__global__ __launch_bounds__(256) void transpose_cast(const float* __restrict__ in,
                                                      unsigned short* __restrict__ out,
                                                      int R, int Cc) {
  __shared__ float t[32][33];
  const int bx = blockIdx.x * 32, by = blockIdx.y * 32;
  const int tx = threadIdx.x & 31, ty = threadIdx.x >> 5;
  #pragma unroll
  for (int j = 0; j < 32; j += 8)
    t[ty + j][tx] = in[(size_t)(by + ty + j) * Cc + bx + tx];
  __syncthreads();
  #pragma unroll
  for (int j = 0; j < 32; j += 8)
    out[(size_t)(bx + ty + j) * R + by + tx] = f2b(t[tx][ty + j]);
}

// ---------------------------------------------------------------------------
// Flash attention: transposed-S, max-free softmax, 8-wave (512-thread) blocks.
// Double-buffered K/V tiles staged via global_load_lds (linear LDS, XOR
// swizzle baked into global K/V layout); counted vmcnt(4) + raw s_barrier;
// setprio around MFMA clusters. (unchanged from round 3 — improved ~16 µs)
// ---------------------------------------------------------------------------
__global__ __launch_bounds__(512, 4) void attn_st(unsigned short* __restrict__ qk,
                                                  const unsigned short* __restrict__ vt) {
  // 2 buffers x (K [64][128] + V^T [128][64]) = 2 x 16384 shorts = 64 KiB.
  // Epilogue reuses [0..17408) as Os[128][136].
  __shared__ __align__(16) unsigned short smem[32768];

  const int tid = threadIdx.x;
  const int w = tid >> 6, lane = tid & 63;
  const int ln = lane & 15, lq = lane >> 4;
  const int b = blockIdx.z, h = blockIdx.y;
  const int j = (b == 0) ? (15 - (int)blockIdx.x) : (int)blockIdx.x;
  const int qb0 = j * 128;
  const float EXPSC = 0.08838834764831845f * 1.4426950408889634f;
  const int xsw = (ln & 7) << 3;   // read-side XOR (row&7 == ln&7 for both K and V reads)

  // Q fragments (B-operand: n=ln=query, k=lq*8..) straight from global, once
  const int wq0 = qb0 + w * 16;
  const int qg = wq0 + ln;
  const unsigned short* Qp = qk + (size_t)(b * T_SEQ + qg) * LQK + h * HD + lq * 8;
  bf16x8 bq[4];
  #pragma unroll
  for (int ks = 0; ks < 4; ++ks) bq[ks] = *(const bf16x8*)(Qp + ks * 32);

  // staging bases (global layouts pre-swizzled -> linear row copies)
  const unsigned short* Kg = qk + (size_t)(b * T_SEQ) * LQK + C_EMB + h * HD;
  const unsigned short* Vg = vt + ((size_t)(b * NH + h) * HD) * T_SEQ;
  const int krow = tid >> 4, kc16 = (tid & 15) * 8;   // K: 32 rows/chunk x 16 slots
  const int vrow = tid >> 3, vc16 = (tid & 7) * 8;    // V: 64 rows/chunk x 8 slots

  f32x4 ot[8];  // O^T accum: regs = d = dt*16+lq*4+r, col = query ln
  #pragma unroll
  for (int dt = 0; dt < 8; ++dt) ot[dt] = (f32x4){0.f, 0.f, 0.f, 0.f};
  float l_i = 0.f;

  // prologue: stage tiles 0 (buf0) and 1 (buf1): 4 cp16/thread each
  {
    unsigned short* b0 = smem;
    async_cp16(Kg + (size_t)(0 * 64 + krow) * LQK + kc16,        b0 + tid * 8);
    async_cp16(Kg + (size_t)(0 * 64 + krow + 32) * LQK + kc16,   b0 + 4096 + tid * 8);
    async_cp16(Vg + (size_t)vrow * T_SEQ + 0 * 64 + vc16,        b0 + 8192 + tid * 8);
    async_cp16(Vg + (size_t)(vrow + 64) * T_SEQ + 0 * 64 + vc16, b0 + 12288 + tid * 8);
    unsigned short* b1 = smem + 16384;
    async_cp16(Kg + (size_t)(1 * 64 + krow) * LQK + kc16,        b1 + tid * 8);
    async_cp16(Kg + (size_t)(1 * 64 + krow + 32) * LQK + kc16,   b1 + 4096 + tid * 8);
    async_cp16(Vg + (size_t)vrow * T_SEQ + 1 * 64 + vc16,        b1 + 8192 + tid * 8);
    async_cp16(Vg + (size_t)(vrow + 64) * T_SEQ + 1 * 64 + vc16, b1 + 12288 + tid * 8);
  }

  const int kbmax = 2 * j + 1;
  for (int kb = 0; kb <= kbmax; ++kb) {
    asm volatile("s_waitcnt vmcnt(4)" ::: "memory");  // tile kb landed (tile kb+1 in flight)
    __builtin_amdgcn_s_barrier();
    __builtin_amdgcn_sched_barrier(0);
    const unsigned short* Ksb = smem + (kb & 1) * 16384;
    const unsigned short* Vsb = Ksb + 8192;

    if (kb * 64 <= wq0 + 15) {            // wave has unmasked work this block
      const bool diag = (kb * 64 + 63 > wq0);

      // ---- S^T = K Q^T
      f32x4 st[4];
      __builtin_amdgcn_s_setprio(1);
      #pragma unroll
      for (int kt = 0; kt < 4; ++kt) {
        st[kt] = (f32x4){0.f, 0.f, 0.f, 0.f};
        #pragma unroll
        for (int ks = 0; ks < 4; ++ks) {
          bf16x8 ak = *(const bf16x8*)(Ksb + (kt * 16 + ln) * 128 + ((ks * 32 + lq * 8) ^ xsw));
          st[kt] = __builtin_amdgcn_mfma_f32_16x16x32_bf16(ak, bq[ks], st[kt], 0, 0, 0);
        }
      }
      __builtin_amdgcn_s_setprio(0);

      // ---- max-free softmax: p = exp2(s*EXPSC); zero masked; accumulate l
      short4v pf[4];
      #pragma unroll
      for (int kt = 0; kt < 4; ++kt)
        #pragma unroll
        for (int r = 0; r < 4; ++r) {
          float p = __builtin_exp2f(st[kt][r] * EXPSC);
          if (diag && (kb * 64 + kt * 16 + lq * 4 + r > qg)) p = 0.f;
          l_i += p;
          pf[kt][r] = (short)f2b(p);
        }

      // ---- O^T += V^T P^T : K=16 MFMA, P straight from registers
      __builtin_amdgcn_s_setprio(1);
      #pragma unroll
      for (int kt = 0; kt < 4; ++kt)
        #pragma unroll
        for (int dt = 0; dt < 8; ++dt) {
          short4v av = *(const short4v*)(Vsb + (dt * 16 + ln) * 64 + ((kt * 16 + lq * 4) ^ xsw));
          ot[dt] = __builtin_amdgcn_mfma_f32_16x16x16bf16_1k(av, pf[kt], ot[dt], 0, 0, 0);
        }
      __builtin_amdgcn_s_setprio(0);
    }

    __builtin_amdgcn_s_barrier();        // all waves done reading buf[kb&1]
    __builtin_amdgcn_sched_barrier(0);
    const int kn = (kb + 2 <= kbmax) ? (kb + 2) : kbmax;  // clamp keeps queue depth
    unsigned short* dst = smem + (kb & 1) * 16384;
    async_cp16(Kg + (size_t)(kn * 64 + krow) * LQK + kc16,        dst + tid * 8);
    async_cp16(Kg + (size_t)(kn * 64 + krow + 32) * LQK + kc16,   dst + 4096 + tid * 8);
    async_cp16(Vg + (size_t)vrow * T_SEQ + kn * 64 + vc16,        dst + 8192 + tid * 8);
    async_cp16(Vg + (size_t)(vrow + 64) * T_SEQ + kn * 64 + vc16, dst + 12288 + tid * 8);
  }

  // ---- final l reduction across the 4 partner lanes (once)
  l_i += __shfl_xor(l_i, 16);
  l_i += __shfl_xor(l_i, 32);
  const float inv = 1.f / l_i;

  // ---- epilogue: O^T -> O via LDS (smem as Os[128][136]), coalesced store.
  // Drain in-flight staging before reusing smem.
  asm volatile("s_waitcnt vmcnt(0)" ::: "memory");
  __syncthreads();
  #pragma unroll
  for (int dt = 0; dt < 8; ++dt) {
    ushort4 p4;
    p4.x = f2b(ot[dt][0] * inv); p4.y = f2b(ot[dt][1] * inv);
    p4.z = f2b(ot[dt][2] * inv); p4.w = f2b(ot[dt][3] * inv);
    *(ushort4*)(smem + (w * 16 + ln) * 136 + dt * 16 + lq * 4) = p4;
  }
  __syncthreads();
  #pragma unroll
  for (int jj = 0; jj < 4; ++jj) {        // 128 rows x 16 uint4 = 2048 items
    const int s = tid + jj * 512;
    const int row = s >> 4, c8 = s & 15;
    *(uint4*)(qk + (size_t)(b * T_SEQ + qb0 + row) * LQK + h * HD + c8 * 8) =
        *(const uint4*)(smem + row * 136 + c8 * 8);
  }
}

// ---------------------------------------------------------------- launch
extern "C" void kernel_launch(void* const* d_in, const int* in_sizes, int n_in,
                              void* d_out, int out_size, void* d_ws, size_t ws_size,
                              hipStream_t stream) {
  (void)in_sizes; (void)n_in; (void)out_size;
  const float* x      = (const float*)d_in[0];
  const float* W_attn = (const float*)d_in[1];
  const float* b_attn = (const float*)d_in[2];
  const float* W_proj = (const float*)d_in[3];
  const float* b_proj = (const float*)d_in[4];
  float* out = (float*)d_out;

  char* ws = (char*)d_ws;
  unsigned short* qk = (unsigned short*)(ws);                  // 32 MiB [4096][4096]
  unsigned short* vt = (unsigned short*)(ws + 33554432);       // 16 MiB [B*NH*HD][T]
  unsigned short* xb  = (unsigned short*)(ws + 50331648);      // 16 MiB x bf16
  unsigned short* WaT = (unsigned short*)(ws + 67108864);      // 24 MiB W_attn^T bf16
  unsigned short* WpT = (unsigned short*)(ws + 92274688);      // 8  MiB W_proj^T bf16
  const bool tierA = (ws_size >= 100663296);                   // 96 MiB

  if (tierA) {
    const int n_x = M_ROWS * C_EMB;
    cast_x_bf16<<<n_x / 4 / 256, 256, 0, stream>>>((const float4*)x, (ushort4*)xb, n_x / 4);
    transpose_cast<<<dim3(N_QKV / 32, C_EMB / 32), 256, 0, stream>>>(W_attn, WaT, C_EMB, N_QKV);
    transpose_cast<<<dim3(C_EMB / 32, C_EMB / 32), 256, 0, stream>>>(W_proj, WpT, C_EMB, C_EMB);
    gemm8_bt<1, unsigned short><<<dim3(N_QKV / 256, M_ROWS / 256), 512, 0, stream>>>(
        xb, C_EMB, WaT, C_EMB, b_attn, (unsigned short*)nullptr, 0, qk, vt, C_EMB);
  } else {
    gemm_any<1, float, unsigned short><<<dim3(N_QKV / 128, M_ROWS / 128), 256, 0, stream>>>(
        x, C_EMB, W_attn, N_QKV, b_attn, (unsigned short*)nullptr, 0, qk, vt, N_QKV, C_EMB);
  }

  attn_st<<<dim3(16, NH, B_SZ), 512, 0, stream>>>(qk, vt);

  if (tierA) {
    gemm_bt<0, float><<<dim3(C_EMB / 128, M_ROWS / 128), 256, 0, stream>>>(
        qk, LQK, WpT, b_proj, out, C_EMB, nullptr, nullptr, C_EMB, C_EMB);
  } else {
    gemm_any<0, unsigned short, float><<<dim3(C_EMB / 128, M_ROWS / 128), 256, 0, stream>>>(
        qk, LQK, W_proj, C_EMB, b_proj, out, C_EMB, nullptr, nullptr, C_EMB, C_EMB);
  }
}